// Round 13
// baseline (115.147 us; speedup 1.0000x reference)
//
#include <hip/hip_runtime.h>

#define BATCH 64
#define N_IN  2048
#define NN    512
#define ALPHA 0.995f
#define BETA  0.975f
#define V_TH  2.0f

// ================= G8 primary: kr 0..63 (32 k-rows), bq 0..7 (8 batches) ========
// 512 blocks x 1024 thr, 2/CU, 32 waves/CU. w row loaded once per 8 batches.
// id%8 = kr%8 -> all 8 bq-sharers of a w-slab on one XCD (L2-hot).
__global__ __launch_bounds__(1024, 8)
void k1_stream8(const float* __restrict__ x, const float* __restrict__ w,
                const float* __restrict__ z, const float* __restrict__ z_out,
                float4* __restrict__ ws)
{
    __shared__ __align__(16) float4 red[4][8][128];   // 64 KB, multi-purpose
    const int kr  = blockIdx.x;          // 0..63
    const int b0  = blockIdx.y * 8;
    const int tid = threadIdx.x;
    const int c4  = tid & 127;
    const int kl  = tid >> 7;            // 0..7
    const int k0  = kr * 32 + kl;

    const float4* __restrict__ x4 = (const float4*)x;
    const float4* __restrict__ w4 = (const float4*)w;

    size_t xbase = ((size_t)b0 * N_IN + k0) * 128 + c4;
    const size_t gstr  = (size_t)N_IN * 128;   // batch stride
    size_t woff  = (size_t)k0 * 128 + c4;
    const size_t kstep = 8 * 128;              // 8 k-rows

    float4 acc[8];
#pragma unroll
    for (int g = 0; g < 8; ++g) acc[g] = make_float4(0.f, 0.f, 0.f, 0.f);

#pragma unroll
    for (int i = 0; i < 4; ++i) {        // 4 x 8 = 32 k-rows
        float4 xv[4];
#pragma unroll
        for (int u = 0; u < 4; ++u) xv[u] = x4[xbase + u * gstr];
        const float4 wv = w4[woff];
#pragma unroll
        for (int u = 0; u < 4; ++u) {
            acc[u].x += xv[u].x * wv.x;  acc[u].y += xv[u].y * wv.y;
            acc[u].z += xv[u].z * wv.z;  acc[u].w += xv[u].w * wv.w;
        }
#pragma unroll
        for (int u = 0; u < 4; ++u) xv[u] = x4[xbase + (4 + u) * gstr];
#pragma unroll
        for (int u = 0; u < 4; ++u) {
            acc[4+u].x += xv[u].x * wv.x;  acc[4+u].y += xv[u].y * wv.y;
            acc[4+u].z += xv[u].z * wv.z;  acc[4+u].w += xv[u].w * wv.w;
        }
        xbase += kstep;
        woff  += kstep;
    }

    // ---- column sums in two half-G passes over one 64 KB buffer
    float4 s0 = make_float4(0.f, 0.f, 0.f, 0.f);
    float4 s1 = make_float4(0.f, 0.f, 0.f, 0.f);
    const int gg = tid >> 7, cc = tid & 127;   // (g, c) for tid<512

#pragma unroll
    for (int q = 0; q < 4; ++q) red[q][kl][c4] = acc[q];
    __syncthreads();
    if (tid < 512) {
        s0 = red[gg][0][cc];
#pragma unroll
        for (int l = 1; l < 8; ++l) {
            const float4 o = red[gg][l][cc];
            s0.x += o.x; s0.y += o.y; s0.z += o.z; s0.w += o.w;
        }
    }
    __syncthreads();
#pragma unroll
    for (int q = 0; q < 4; ++q) red[q][kl][c4] = acc[4 + q];
    __syncthreads();
    if (tid < 512) {
        s1 = red[gg][0][cc];
#pragma unroll
        for (int l = 1; l < 8; ++l) {
            const float4 o = red[gg][l][cc];
            s1.x += o.x; s1.y += o.y; s1.z += o.z; s1.w += o.w;
        }
    }
    __syncthreads();                     // red free for drive2 reuse

    // ---- drive2 j-slice [8kr, 8kr+8) for this block's 8 batches
    float* d2l = (float*)red;            // [8][512] floats = 16 KB
    float* zr  = d2l + 8 * NN;           // [8][9]
    const int j0 = kr * 8;

    if (tid < 8 * 9) {
        const int g = tid / 9, jj = tid % 9;
        const int idx = j0 + jj;
        if (idx < NN)
            zr[g * 9 + jj] = BETA * z_out[(b0 + g) * NN + idx]
                           + z[(b0 + g) * NN + idx];
    }
    __syncthreads();

    {
        const int n  = tid & 511;
        const int gh = tid >> 9;         // 0/1 -> batches 0-3 / 4-7
        float p[4] = {0.f, 0.f, 0.f, 0.f};
        const int jend = (j0 + 8 < NN - 1) ? j0 + 8 : NN - 1;
        for (int j = j0; j < jend; ++j) {
            const float wv = w[(size_t)(N_IN + j) * NN + n];  // coalesced, L2-hot
            const int jj = j + (j >= n) - j0;
#pragma unroll
            for (int q = 0; q < 4; ++q)
                p[q] += zr[(gh * 4 + q) * 9 + jj] * wv;
        }
#pragma unroll
        for (int q = 0; q < 4; ++q) d2l[(gh * 4 + q) * NN + n] = p[q];
    }
    __syncthreads();

    if (tid < 512) {                     // combine and store both half-G partials
        s0.x += d2l[gg * NN + 4 * cc + 0];
        s0.y += d2l[gg * NN + 4 * cc + 1];
        s0.z += d2l[gg * NN + 4 * cc + 2];
        s0.w += d2l[gg * NN + 4 * cc + 3];
        s1.x += d2l[(4 + gg) * NN + 4 * cc + 0];
        s1.y += d2l[(4 + gg) * NN + 4 * cc + 1];
        s1.z += d2l[(4 + gg) * NN + 4 * cc + 2];
        s1.w += d2l[(4 + gg) * NN + 4 * cc + 3];
        ws[((size_t)kr * BATCH + b0 + gg) * 128 + cc]     = s0;
        ws[((size_t)kr * BATCH + b0 + 4 + gg) * 128 + cc] = s1;
    }
}

// ================= G4 path (R12-proven, 4 MB ws) =================
__global__ __launch_bounds__(1024, 8)
void k1_stream4(const float* __restrict__ x, const float* __restrict__ w,
                const float* __restrict__ z, const float* __restrict__ z_out,
                float4* __restrict__ ws)
{
    __shared__ __align__(16) float4 red[4][8][128];
    const int kr  = blockIdx.x;          // 0..31
    const int b0  = blockIdx.y * 4;
    const int tid = threadIdx.x;
    const int c4  = tid & 127;
    const int kl  = tid >> 7;
    const int k0  = kr * 64 + kl;

    const float4* __restrict__ x4 = (const float4*)x;
    const float4* __restrict__ w4 = (const float4*)w;

    size_t xoff[4];
#pragma unroll
    for (int g = 0; g < 4; ++g)
        xoff[g] = ((size_t)(b0 + g) * N_IN + k0) * 128 + c4;
    size_t woff = (size_t)k0 * 128 + c4;
    const size_t kstep = 8 * 128;

    float4 acc[4];
#pragma unroll
    for (int g = 0; g < 4; ++g) acc[g] = make_float4(0.f, 0.f, 0.f, 0.f);

#pragma unroll 2
    for (int i = 0; i < 8; ++i) {
        float4 xv[4];
#pragma unroll
        for (int g = 0; g < 4; ++g) xv[g] = x4[xoff[g]];
        const float4 wv = w4[woff];
#pragma unroll
        for (int g = 0; g < 4; ++g) {
            acc[g].x += xv[g].x * wv.x;  acc[g].y += xv[g].y * wv.y;
            acc[g].z += xv[g].z * wv.z;  acc[g].w += xv[g].w * wv.w;
        }
#pragma unroll
        for (int g = 0; g < 4; ++g) xoff[g] += kstep;
        woff += kstep;
    }

#pragma unroll
    for (int g = 0; g < 4; ++g) red[g][kl][c4] = acc[g];
    __syncthreads();

    float4 s = make_float4(0.f, 0.f, 0.f, 0.f);
    if (tid < 512) {
        const int g = tid >> 7, c = tid & 127;
        s = red[g][0][c];
#pragma unroll
        for (int l = 1; l < 8; ++l) {
            const float4 o = red[g][l][c];
            s.x += o.x; s.y += o.y; s.z += o.z; s.w += o.w;
        }
    }
    __syncthreads();

    float* d2l = (float*)red;
    float* zr  = d2l + 4 * NN;
    const int j0 = kr * 16;

    if (tid < 4 * 17) {
        const int g = tid / 17, jj = tid % 17;
        const int idx = j0 + jj;
        if (idx < NN)
            zr[g * 17 + jj] = BETA * z_out[(b0 + g) * NN + idx]
                            + z[(b0 + g) * NN + idx];
    }
    __syncthreads();

    {
        const int n  = tid & 511;
        const int gh = tid >> 9;
        float p0 = 0.f, p1 = 0.f;
        const int jend = (j0 + 16 < NN - 1) ? j0 + 16 : NN - 1;
        for (int j = j0; j < jend; ++j) {
            const float wv = w[(size_t)(N_IN + j) * NN + n];
            const int jj = j + (j >= n) - j0;
            p0 += zr[(gh * 2 + 0) * 17 + jj] * wv;
            p1 += zr[(gh * 2 + 1) * 17 + jj] * wv;
        }
        d2l[(gh * 2 + 0) * NN + n] = p0;
        d2l[(gh * 2 + 1) * NN + n] = p1;
    }
    __syncthreads();

    if (tid < 512) {
        const int g = tid >> 7, c = tid & 127;
        s.x += d2l[g * NN + 4 * c + 0];
        s.y += d2l[g * NN + 4 * c + 1];
        s.z += d2l[g * NN + 4 * c + 2];
        s.w += d2l[g * NN + 4 * c + 3];
        ws[((size_t)kr * BATCH + b0 + g) * 128 + c] = s;
    }
}

// ================= K3: pure epilogue =================
template <int KRV>
__global__ __launch_bounds__(128)
void k3_epi(const float* __restrict__ v, const float* __restrict__ z,
            const float* __restrict__ z_out, const float* __restrict__ ws,
            float* __restrict__ out)
{
    const int i = blockIdx.x * 128 + threadIdx.x;
    float d = 0.f;
#pragma unroll
    for (int kr = 0; kr < KRV; ++kr)
        d += ws[(size_t)kr * (BATCH * NN) + i];
    const float zz = z[i];
    const float vn = ALPHA * v[i] + d - V_TH * zz;
    out[i]                  = vn;
    out[BATCH * NN + i]     = (vn - V_TH > 0.f) ? 1.f : 0.f;
    out[2 * BATCH * NN + i] = BETA * z_out[i] + zz;
}

// ================= two-kernel fallback (1 MB ws, R10-proven) =================
__global__ __launch_bounds__(1024, 8)
void k1_fallback(const float* __restrict__ x, const float* __restrict__ w,
                 float4* __restrict__ ws)
{
    const int nc  = blockIdx.x;
    const int b0  = blockIdx.y * 4;
    const int kr  = blockIdx.z;
    const int tid = threadIdx.x;
    const int nl  = tid & 15;
    const int kk  = tid >> 4;
    const int wid  = tid >> 6;
    const int lane = tid & 63;

    const float4* __restrict__ x4 = (const float4*)x;
    const float4* __restrict__ w4 = (const float4*)w;
    const int c4    = nc * 16 + nl;
    const int kbase = kr * 512 + kk;

    size_t xoff[4];
#pragma unroll
    for (int g = 0; g < 4; ++g)
        xoff[g] = ((size_t)(b0 + g) * N_IN + kbase) * 128 + c4;
    size_t woff = (size_t)kbase * 128 + c4;
    const size_t kstep = (size_t)64 * 128;

    float4 acc[4];
#pragma unroll
    for (int g = 0; g < 4; ++g) acc[g] = make_float4(0.f, 0.f, 0.f, 0.f);

#pragma unroll 2
    for (int i = 0; i < 8; ++i) {
        float4 xv[4];
#pragma unroll
        for (int g = 0; g < 4; ++g) xv[g] = x4[xoff[g]];
        const float4 wv = w4[woff];
#pragma unroll
        for (int g = 0; g < 4; ++g) {
            acc[g].x += xv[g].x * wv.x;  acc[g].y += xv[g].y * wv.y;
            acc[g].z += xv[g].z * wv.z;  acc[g].w += xv[g].w * wv.w;
        }
#pragma unroll
        for (int g = 0; g < 4; ++g) xoff[g] += kstep;
        woff += kstep;
    }

#pragma unroll
    for (int off = 32; off >= 16; off >>= 1) {
#pragma unroll
        for (int g = 0; g < 4; ++g) {
            acc[g].x += __shfl_down(acc[g].x, off);
            acc[g].y += __shfl_down(acc[g].y, off);
            acc[g].z += __shfl_down(acc[g].z, off);
            acc[g].w += __shfl_down(acc[g].w, off);
        }
    }

    __shared__ float4 wpart[16][4][16];
    if (lane < 16) {
#pragma unroll
        for (int g = 0; g < 4; ++g) wpart[wid][g][lane] = acc[g];
    }
    __syncthreads();

    if (tid < 64) {
        const int g = tid >> 4, c = tid & 15;
        float4 sf = wpart[0][g][c];
#pragma unroll
        for (int ww = 1; ww < 16; ++ww) {
            const float4 o = wpart[ww][g][c];
            sf.x += o.x; sf.y += o.y; sf.z += o.z; sf.w += o.w;
        }
        ws[((size_t)kr * BATCH + b0 + g) * 128 + nc * 16 + c] = sf;
    }
}

__global__ __launch_bounds__(1024)
void k2_finish(const float* __restrict__ v, const float* __restrict__ z,
               const float* __restrict__ z_out, const float* __restrict__ w,
               const float* __restrict__ ws, float* __restrict__ out)
{
    const int nc  = blockIdx.x;
    const int b   = blockIdx.y;
    const int nb  = nc * 64;
    const int tid = threadIdx.x;

    __shared__ float zlds[NN];
    __shared__ float r2[1024];

    if (tid < NN)
        zlds[tid] = BETA * z_out[b * NN + tid] + z[b * NN + tid];
    __syncthreads();

    const int n_loc = tid & 63;
    const int n     = nb + n_loc;
    const int jg    = tid >> 6;
    float d2 = 0.f;
#pragma unroll 4
    for (int j = jg; j < NN - 1; j += 16)
        d2 += zlds[j + (j >= n)] * w[(size_t)(N_IN + j) * NN + n];
    r2[tid] = d2;
    __syncthreads();

    if (tid < 64) {
        float d1 = 0.f;
#pragma unroll
        for (int kr = 0; kr < 4; ++kr)
            d1 += ws[((size_t)kr * BATCH + b) * NN + n];
        float d2s = 0.f;
#pragma unroll
        for (int g = 0; g < 16; ++g) d2s += r2[g * 64 + n_loc];
        const float vv    = v[b * NN + n];
        const float zz    = z[b * NN + n];
        const float v_new = ALPHA * vv + d1 + d2s - V_TH * zz;
        out[b * NN + n]                  = v_new;
        out[BATCH * NN + b * NN + n]     = (v_new - V_TH > 0.f) ? 1.f : 0.f;
        out[2 * BATCH * NN + b * NN + n] = zlds[n];
    }
}

extern "C" void kernel_launch(void* const* d_in, const int* in_sizes, int n_in,
                              void* d_out, int out_size, void* d_ws, size_t ws_size,
                              hipStream_t stream) {
    (void)in_sizes; (void)n_in; (void)out_size;
    const float* x     = (const float*)d_in[0];
    const float* v     = (const float*)d_in[1];
    const float* z     = (const float*)d_in[2];
    const float* z_out = (const float*)d_in[3];
    const float* w     = (const float*)d_in[4];
    float* out = (float*)d_out;
    float* wsf = (float*)d_ws;

    const size_t need64 = (size_t)64 * BATCH * NN * sizeof(float);   // 8 MB
    const size_t need32 = (size_t)32 * BATCH * NN * sizeof(float);   // 4 MB
    if (ws_size >= need64) {
        dim3 g1(64, 8);                  // 512 blocks
        k1_stream8<<<g1, 1024, 0, stream>>>(x, w, z, z_out, (float4*)wsf);
        k3_epi<64><<<BATCH * NN / 128, 128, 0, stream>>>(v, z, z_out, wsf, out);
    } else if (ws_size >= need32) {
        dim3 g1(32, 16);                 // R12 path
        k1_stream4<<<g1, 1024, 0, stream>>>(x, w, z, z_out, (float4*)wsf);
        k3_epi<32><<<BATCH * NN / 128, 128, 0, stream>>>(v, z, z_out, wsf, out);
    } else {
        dim3 g1(8, 16, 4);
        k1_fallback<<<g1, 1024, 0, stream>>>(x, w, (float4*)wsf);
        dim3 g2(8, BATCH);
        k2_finish<<<g2, 1024, 0, stream>>>(v, z, z_out, w, wsf, out);
    }
}

// Round 14
// 64.854 us; speedup vs baseline: 1.7755x; 1.7755x over previous
//
#include <hip/hip_runtime.h>

#define BATCH 64
#define N_IN  2048
#define NN    512
#define ALPHA 0.995f
#define BETA  0.975f
#define V_TH  2.0f

// ========== G8 half-split primary: kr 0..63 (32 k-rows), bq 0..7 ==========
// 512 blocks x 1024 thr. Two 512-thread halves; each half owns 4 batches with
// acc[4] (R12-proven register pressure). Both halves load the SAME w rows:
// second hit comes from L1 -> w HBM/L2 traffic halves vs G4.
__global__ __launch_bounds__(1024, 8)
void k1_stream8h(const float* __restrict__ x, const float* __restrict__ w,
                 const float* __restrict__ z, const float* __restrict__ z_out,
                 float4* __restrict__ ws)
{
    __shared__ __align__(16) float4 red[2][4][4][128];   // 64 KB, multi-purpose
    const int kr   = blockIdx.x;         // 0..63
    const int bq   = blockIdx.y;         // 0..7
    const int tid  = threadIdx.x;
    const int half = tid >> 9;           // 0/1
    const int t    = tid & 511;
    const int kl   = t >> 7;             // 0..3
    const int c4   = t & 127;
    const int b0h  = bq * 8 + half * 4;  // this half's first batch
    const int k0   = kr * 32 + kl;

    const float4* __restrict__ x4 = (const float4*)x;
    const float4* __restrict__ w4 = (const float4*)w;

    size_t xoff[4];
#pragma unroll
    for (int g = 0; g < 4; ++g)
        xoff[g] = ((size_t)(b0h + g) * N_IN + k0) * 128 + c4;
    size_t woff = (size_t)k0 * 128 + c4;
    const size_t kstep = 4 * 128;        // 4 k-rows per iter

    float4 acc[4];
#pragma unroll
    for (int g = 0; g < 4; ++g) acc[g] = make_float4(0.f, 0.f, 0.f, 0.f);

#pragma unroll 2
    for (int i = 0; i < 8; ++i) {        // 8 x 4 = 32 k-rows
        float4 xv[4];
#pragma unroll
        for (int g = 0; g < 4; ++g) xv[g] = x4[xoff[g]];   // HBM streams first
        const float4 wv = w4[woff];                        // L1/L2-hot second
#pragma unroll
        for (int g = 0; g < 4; ++g) {
            acc[g].x += xv[g].x * wv.x;  acc[g].y += xv[g].y * wv.y;
            acc[g].z += xv[g].z * wv.z;  acc[g].w += xv[g].w * wv.w;
        }
#pragma unroll
        for (int g = 0; g < 4; ++g) xoff[g] += kstep;
        woff += kstep;
    }

    // ---- single-pass column sums: all 1024 threads own one (half', g, c)
#pragma unroll
    for (int g = 0; g < 4; ++g) red[half][g][kl][c4] = acc[g];
    __syncthreads();

    const int rh = tid >> 9, rg = (tid >> 7) & 3, rc = tid & 127;
    float4 s = red[rh][rg][0][rc];
#pragma unroll
    for (int l = 1; l < 4; ++l) {
        const float4 o = red[rh][rg][l][rc];
        s.x += o.x; s.y += o.y; s.z += o.z; s.w += o.w;
    }
    __syncthreads();                     // red free for drive2 reuse

    // ---- drive2 j-slice [8kr, 8kr+8) for this block's 8 batches
    float* d2l = (float*)red;            // [8][512] floats = 16 KB
    float* zr  = d2l + 8 * NN;           // [8][9]
    const int j0 = kr * 8;
    const int b0 = bq * 8;

    if (tid < 8 * 9) {
        const int g = tid / 9, jj = tid % 9;
        const int idx = j0 + jj;
        if (idx < NN)
            zr[g * 9 + jj] = BETA * z_out[(b0 + g) * NN + idx]
                           + z[(b0 + g) * NN + idx];
    }
    __syncthreads();

    {
        const int n  = tid & 511;
        const int gh = tid >> 9;         // 0/1 -> batches 0-3 / 4-7
        float p[4] = {0.f, 0.f, 0.f, 0.f};
        const int jend = (j0 + 8 < NN - 1) ? j0 + 8 : NN - 1;
        for (int j = j0; j < jend; ++j) {
            const float wv = w[(size_t)(N_IN + j) * NN + n];  // coalesced, L2-hot
            const int jj = j + (j >= n) - j0;
#pragma unroll
            for (int q = 0; q < 4; ++q)
                p[q] += zr[(gh * 4 + q) * 9 + jj] * wv;
        }
#pragma unroll
        for (int q = 0; q < 4; ++q) d2l[(gh * 4 + q) * NN + n] = p[q];
    }
    __syncthreads();

    // ---- combine d1 + d2 partials and store (thread owns (rh, rg, rc))
    {
        const int gb = rh * 4 + rg;      // batch index within bq group 0..7
        s.x += d2l[gb * NN + 4 * rc + 0];
        s.y += d2l[gb * NN + 4 * rc + 1];
        s.z += d2l[gb * NN + 4 * rc + 2];
        s.w += d2l[gb * NN + 4 * rc + 3];
        ws[((size_t)kr * BATCH + b0 + gb) * 128 + rc] = s;
    }
}

// ================= G4 path (R12-proven, 4 MB ws) =================
__global__ __launch_bounds__(1024, 8)
void k1_stream4(const float* __restrict__ x, const float* __restrict__ w,
                const float* __restrict__ z, const float* __restrict__ z_out,
                float4* __restrict__ ws)
{
    __shared__ __align__(16) float4 red[4][8][128];
    const int kr  = blockIdx.x;          // 0..31
    const int b0  = blockIdx.y * 4;
    const int tid = threadIdx.x;
    const int c4  = tid & 127;
    const int kl  = tid >> 7;
    const int k0  = kr * 64 + kl;

    const float4* __restrict__ x4 = (const float4*)x;
    const float4* __restrict__ w4 = (const float4*)w;

    size_t xoff[4];
#pragma unroll
    for (int g = 0; g < 4; ++g)
        xoff[g] = ((size_t)(b0 + g) * N_IN + k0) * 128 + c4;
    size_t woff = (size_t)k0 * 128 + c4;
    const size_t kstep = 8 * 128;

    float4 acc[4];
#pragma unroll
    for (int g = 0; g < 4; ++g) acc[g] = make_float4(0.f, 0.f, 0.f, 0.f);

#pragma unroll 2
    for (int i = 0; i < 8; ++i) {
        float4 xv[4];
#pragma unroll
        for (int g = 0; g < 4; ++g) xv[g] = x4[xoff[g]];
        const float4 wv = w4[woff];
#pragma unroll
        for (int g = 0; g < 4; ++g) {
            acc[g].x += xv[g].x * wv.x;  acc[g].y += xv[g].y * wv.y;
            acc[g].z += xv[g].z * wv.z;  acc[g].w += xv[g].w * wv.w;
        }
#pragma unroll
        for (int g = 0; g < 4; ++g) xoff[g] += kstep;
        woff += kstep;
    }

#pragma unroll
    for (int g = 0; g < 4; ++g) red[g][kl][c4] = acc[g];
    __syncthreads();

    float4 s = make_float4(0.f, 0.f, 0.f, 0.f);
    if (tid < 512) {
        const int g = tid >> 7, c = tid & 127;
        s = red[g][0][c];
#pragma unroll
        for (int l = 1; l < 8; ++l) {
            const float4 o = red[g][l][c];
            s.x += o.x; s.y += o.y; s.z += o.z; s.w += o.w;
        }
    }
    __syncthreads();

    float* d2l = (float*)red;
    float* zr  = d2l + 4 * NN;
    const int j0 = kr * 16;

    if (tid < 4 * 17) {
        const int g = tid / 17, jj = tid % 17;
        const int idx = j0 + jj;
        if (idx < NN)
            zr[g * 17 + jj] = BETA * z_out[(b0 + g) * NN + idx]
                            + z[(b0 + g) * NN + idx];
    }
    __syncthreads();

    {
        const int n  = tid & 511;
        const int gh = tid >> 9;
        float p0 = 0.f, p1 = 0.f;
        const int jend = (j0 + 16 < NN - 1) ? j0 + 16 : NN - 1;
        for (int j = j0; j < jend; ++j) {
            const float wv = w[(size_t)(N_IN + j) * NN + n];
            const int jj = j + (j >= n) - j0;
            p0 += zr[(gh * 2 + 0) * 17 + jj] * wv;
            p1 += zr[(gh * 2 + 1) * 17 + jj] * wv;
        }
        d2l[(gh * 2 + 0) * NN + n] = p0;
        d2l[(gh * 2 + 1) * NN + n] = p1;
    }
    __syncthreads();

    if (tid < 512) {
        const int g = tid >> 7, c = tid & 127;
        s.x += d2l[g * NN + 4 * c + 0];
        s.y += d2l[g * NN + 4 * c + 1];
        s.z += d2l[g * NN + 4 * c + 2];
        s.w += d2l[g * NN + 4 * c + 3];
        ws[((size_t)kr * BATCH + b0 + g) * 128 + c] = s;
    }
}

// ================= K3: pure epilogue =================
template <int KRV>
__global__ __launch_bounds__(128)
void k3_epi(const float* __restrict__ v, const float* __restrict__ z,
            const float* __restrict__ z_out, const float* __restrict__ ws,
            float* __restrict__ out)
{
    const int i = blockIdx.x * 128 + threadIdx.x;
    float d = 0.f;
#pragma unroll
    for (int kr = 0; kr < KRV; ++kr)
        d += ws[(size_t)kr * (BATCH * NN) + i];
    const float zz = z[i];
    const float vn = ALPHA * v[i] + d - V_TH * zz;
    out[i]                  = vn;
    out[BATCH * NN + i]     = (vn - V_TH > 0.f) ? 1.f : 0.f;
    out[2 * BATCH * NN + i] = BETA * z_out[i] + zz;
}

// ================= two-kernel fallback (1 MB ws, R10-proven) =================
__global__ __launch_bounds__(1024, 8)
void k1_fallback(const float* __restrict__ x, const float* __restrict__ w,
                 float4* __restrict__ ws)
{
    const int nc  = blockIdx.x;
    const int b0  = blockIdx.y * 4;
    const int kr  = blockIdx.z;
    const int tid = threadIdx.x;
    const int nl  = tid & 15;
    const int kk  = tid >> 4;
    const int wid  = tid >> 6;
    const int lane = tid & 63;

    const float4* __restrict__ x4 = (const float4*)x;
    const float4* __restrict__ w4 = (const float4*)w;
    const int c4    = nc * 16 + nl;
    const int kbase = kr * 512 + kk;

    size_t xoff[4];
#pragma unroll
    for (int g = 0; g < 4; ++g)
        xoff[g] = ((size_t)(b0 + g) * N_IN + kbase) * 128 + c4;
    size_t woff = (size_t)kbase * 128 + c4;
    const size_t kstep = (size_t)64 * 128;

    float4 acc[4];
#pragma unroll
    for (int g = 0; g < 4; ++g) acc[g] = make_float4(0.f, 0.f, 0.f, 0.f);

#pragma unroll 2
    for (int i = 0; i < 8; ++i) {
        float4 xv[4];
#pragma unroll
        for (int g = 0; g < 4; ++g) xv[g] = x4[xoff[g]];
        const float4 wv = w4[woff];
#pragma unroll
        for (int g = 0; g < 4; ++g) {
            acc[g].x += xv[g].x * wv.x;  acc[g].y += xv[g].y * wv.y;
            acc[g].z += xv[g].z * wv.z;  acc[g].w += xv[g].w * wv.w;
        }
#pragma unroll
        for (int g = 0; g < 4; ++g) xoff[g] += kstep;
        woff += kstep;
    }

#pragma unroll
    for (int off = 32; off >= 16; off >>= 1) {
#pragma unroll
        for (int g = 0; g < 4; ++g) {
            acc[g].x += __shfl_down(acc[g].x, off);
            acc[g].y += __shfl_down(acc[g].y, off);
            acc[g].z += __shfl_down(acc[g].z, off);
            acc[g].w += __shfl_down(acc[g].w, off);
        }
    }

    __shared__ float4 wpart[16][4][16];
    if (lane < 16) {
#pragma unroll
        for (int g = 0; g < 4; ++g) wpart[wid][g][lane] = acc[g];
    }
    __syncthreads();

    if (tid < 64) {
        const int g = tid >> 4, c = tid & 15;
        float4 sf = wpart[0][g][c];
#pragma unroll
        for (int ww = 1; ww < 16; ++ww) {
            const float4 o = wpart[ww][g][c];
            sf.x += o.x; sf.y += o.y; sf.z += o.z; sf.w += o.w;
        }
        ws[((size_t)kr * BATCH + b0 + g) * 128 + nc * 16 + c] = sf;
    }
}

__global__ __launch_bounds__(1024)
void k2_finish(const float* __restrict__ v, const float* __restrict__ z,
               const float* __restrict__ z_out, const float* __restrict__ w,
               const float* __restrict__ ws, float* __restrict__ out)
{
    const int nc  = blockIdx.x;
    const int b   = blockIdx.y;
    const int nb  = nc * 64;
    const int tid = threadIdx.x;

    __shared__ float zlds[NN];
    __shared__ float r2[1024];

    if (tid < NN)
        zlds[tid] = BETA * z_out[b * NN + tid] + z[b * NN + tid];
    __syncthreads();

    const int n_loc = tid & 63;
    const int n     = nb + n_loc;
    const int jg    = tid >> 6;
    float d2 = 0.f;
#pragma unroll 4
    for (int j = jg; j < NN - 1; j += 16)
        d2 += zlds[j + (j >= n)] * w[(size_t)(N_IN + j) * NN + n];
    r2[tid] = d2;
    __syncthreads();

    if (tid < 64) {
        float d1 = 0.f;
#pragma unroll
        for (int kr = 0; kr < 4; ++kr)
            d1 += ws[((size_t)kr * BATCH + b) * NN + n];
        float d2s = 0.f;
#pragma unroll
        for (int g = 0; g < 16; ++g) d2s += r2[g * 64 + n_loc];
        const float vv    = v[b * NN + n];
        const float zz    = z[b * NN + n];
        const float v_new = ALPHA * vv + d1 + d2s - V_TH * zz;
        out[b * NN + n]                  = v_new;
        out[BATCH * NN + b * NN + n]     = (v_new - V_TH > 0.f) ? 1.f : 0.f;
        out[2 * BATCH * NN + b * NN + n] = zlds[n];
    }
}

extern "C" void kernel_launch(void* const* d_in, const int* in_sizes, int n_in,
                              void* d_out, int out_size, void* d_ws, size_t ws_size,
                              hipStream_t stream) {
    (void)in_sizes; (void)n_in; (void)out_size;
    const float* x     = (const float*)d_in[0];
    const float* v     = (const float*)d_in[1];
    const float* z     = (const float*)d_in[2];
    const float* z_out = (const float*)d_in[3];
    const float* w     = (const float*)d_in[4];
    float* out = (float*)d_out;
    float* wsf = (float*)d_ws;

    const size_t need64 = (size_t)64 * BATCH * NN * sizeof(float);   // 8 MB
    const size_t need32 = (size_t)32 * BATCH * NN * sizeof(float);   // 4 MB
    if (ws_size >= need64) {
        dim3 g1(64, 8);                  // 512 blocks
        k1_stream8h<<<g1, 1024, 0, stream>>>(x, w, z, z_out, (float4*)wsf);
        k3_epi<64><<<BATCH * NN / 128, 128, 0, stream>>>(v, z, z_out, wsf, out);
    } else if (ws_size >= need32) {
        dim3 g1(32, 16);                 // R12 path
        k1_stream4<<<g1, 1024, 0, stream>>>(x, w, z, z_out, (float4*)wsf);
        k3_epi<32><<<BATCH * NN / 128, 128, 0, stream>>>(v, z, z_out, wsf, out);
    } else {
        dim3 g1(8, 16, 4);
        k1_fallback<<<g1, 1024, 0, stream>>>(x, w, (float4*)wsf);
        dim3 g2(8, BATCH);
        k2_finish<<<g2, 1024, 0, stream>>>(v, z, z_out, w, wsf, out);
    }
}

// Round 15
// 49.728 us; speedup vs baseline: 2.3156x; 1.3042x over previous
//
#include <hip/hip_runtime.h>

#define BATCH 64
#define N_IN  2048
#define NN    512
#define G     4
#define ALPHA 0.995f
#define BETA  0.975f
#define V_TH  2.0f

// ---------------- K1: x-stream (R10-proven) + fold-in of drive2 j-slice ----------
// grid (kr 0..31, bq 0..15) = 512 blocks x 1024 thr, 2/CU, 32 waves/CU.
// Block (kr,bq): d1 partial over k-rows [64kr,64kr+64) AND d2 partial over
// j in [16kr, 16kr+16) for batches b0..b0+3. Both summed into ws[kr][b][n].
__global__ __launch_bounds__(1024, 8)
void k1_stream(const float* __restrict__ x, const float* __restrict__ w,
               const float* __restrict__ z, const float* __restrict__ z_out,
               float4* __restrict__ ws)
{
    __shared__ __align__(16) float4 red[G][8][128];   // 64 KB, reused below
    const int kr  = blockIdx.x;          // 0..31
    const int b0  = blockIdx.y * G;
    const int tid = threadIdx.x;
    const int c4  = tid & 127;
    const int kl  = tid >> 7;

    const float4* __restrict__ x4 = (const float4*)x;
    const float4* __restrict__ w4 = (const float4*)w;
    const int k0 = kr * 64 + kl;

    size_t xoff[G];
#pragma unroll
    for (int g = 0; g < G; ++g)
        xoff[g] = ((size_t)(b0 + g) * N_IN + k0) * 128 + c4;
    size_t woff = (size_t)k0 * 128 + c4;
    const size_t kstep = 8 * 128;

    float4 acc[G];
#pragma unroll
    for (int g = 0; g < G; ++g) acc[g] = make_float4(0.f, 0.f, 0.f, 0.f);

#pragma unroll 2
    for (int i = 0; i < 8; ++i) {        // 64 k-rows
        float4 xv[G];
#pragma unroll
        for (int g = 0; g < G; ++g) xv[g] = x4[xoff[g]];   // HBM streams first
        const float4 wv = w4[woff];                        // L2-hot second
#pragma unroll
        for (int g = 0; g < G; ++g) {
            acc[g].x += xv[g].x * wv.x;
            acc[g].y += xv[g].y * wv.y;
            acc[g].z += xv[g].z * wv.z;
            acc[g].w += xv[g].w * wv.w;
        }
#pragma unroll
        for (int g = 0; g < G; ++g) xoff[g] += kstep;
        woff += kstep;
    }

#pragma unroll
    for (int g = 0; g < G; ++g) red[g][kl][c4] = acc[g];
    __syncthreads();

    // d1 column sums -> registers (threads 0..511 own (g, c4))
    float4 s = make_float4(0.f, 0.f, 0.f, 0.f);
    if (tid < 512) {
        const int g = tid >> 7, c = tid & 127;
        s = red[g][0][c];
#pragma unroll
        for (int l = 1; l < 8; ++l) {
            const float4 o = red[g][l][c];
            s.x += o.x; s.y += o.y; s.z += o.z; s.w += o.w;
        }
    }
    __syncthreads();                     // red free for reuse now

    // ---- drive2 j-slice [j0, j0+16) for this block's 4 batches
    float* d2l = (float*)red;            // [G][512] floats, 8 KB
    float* zr  = d2l + G * NN;           // [G][17] z_out_new slice
    const int j0 = kr * 16;

    if (tid < G * 17) {                  // build z_out_new slice
        const int g = tid / 17, jj = tid % 17;
        const int idx = j0 + jj;
        if (idx < NN)
            zr[g * 17 + jj] = BETA * z_out[(b0 + g) * NN + idx]
                            + z[(b0 + g) * NN + idx];
    }
    __syncthreads();

    {
        const int n  = tid & 511;
        const int gh = tid >> 9;         // 0/1 -> batches {0,1} / {2,3}
        float p0 = 0.f, p1 = 0.f;
        const int jend = (j0 + 16 < NN - 1) ? j0 + 16 : NN - 1;
        for (int j = j0; j < jend; ++j) {
            const float wv = w[(size_t)(N_IN + j) * NN + n];  // coalesced, L2-hot
            const int jj = j + (j >= n) - j0;                 // LOO index in slice
            p0 += zr[(gh * 2 + 0) * 17 + jj] * wv;
            p1 += zr[(gh * 2 + 1) * 17 + jj] * wv;
        }
        d2l[(gh * 2 + 0) * NN + n] = p0;
        d2l[(gh * 2 + 1) * NN + n] = p1;
    }
    __syncthreads();

    if (tid < 512) {                     // combine d1 + d2 partials, store
        const int g = tid >> 7, c = tid & 127;
        s.x += d2l[g * NN + 4 * c + 0];
        s.y += d2l[g * NN + 4 * c + 1];
        s.z += d2l[g * NN + 4 * c + 2];
        s.w += d2l[g * NN + 4 * c + 3];
        ws[((size_t)kr * BATCH + b0 + g) * 128 + c] = s;
    }
}

// ---------------- K3: pure epilogue (sum 32 partials + pointwise) ----------------
__global__ __launch_bounds__(128)
void k3_epi(const float* __restrict__ v, const float* __restrict__ z,
            const float* __restrict__ z_out, const float* __restrict__ ws,
            float* __restrict__ out)
{
    const int i = blockIdx.x * 128 + threadIdx.x;   // 0 .. 64*512-1
    float d = 0.f;
#pragma unroll
    for (int kr = 0; kr < 32; ++kr)
        d += ws[(size_t)kr * (BATCH * NN) + i];     // coalesced, L2-hot
    const float zz = z[i];
    const float vn = ALPHA * v[i] + d - V_TH * zz;
    out[i]                  = vn;
    out[BATCH * NN + i]     = (vn - V_TH > 0.f) ? 1.f : 0.f;
    out[2 * BATCH * NN + i] = BETA * z_out[i] + zz;
}

// ---------------- fallback (ws < 4 MB): R10's proven two-kernel path ----------------
__global__ __launch_bounds__(1024, 8)
void k1_fallback(const float* __restrict__ x, const float* __restrict__ w,
                 float4* __restrict__ ws)
{
    const int nc  = blockIdx.x;
    const int b0  = blockIdx.y * G;
    const int kr  = blockIdx.z;
    const int tid = threadIdx.x;
    const int nl  = tid & 15;
    const int kk  = tid >> 4;
    const int wid  = tid >> 6;
    const int lane = tid & 63;

    const float4* __restrict__ x4 = (const float4*)x;
    const float4* __restrict__ w4 = (const float4*)w;
    const int c4    = nc * 16 + nl;
    const int kbase = kr * 512 + kk;

    size_t xoff[G];
#pragma unroll
    for (int g = 0; g < G; ++g)
        xoff[g] = ((size_t)(b0 + g) * N_IN + kbase) * 128 + c4;
    size_t woff = (size_t)kbase * 128 + c4;
    const size_t kstep = (size_t)64 * 128;

    float4 acc[G];
#pragma unroll
    for (int g = 0; g < G; ++g) acc[g] = make_float4(0.f, 0.f, 0.f, 0.f);

#pragma unroll 2
    for (int i = 0; i < 8; ++i) {
        float4 xv[G];
#pragma unroll
        for (int g = 0; g < G; ++g) xv[g] = x4[xoff[g]];
        const float4 wv = w4[woff];
#pragma unroll
        for (int g = 0; g < G; ++g) {
            acc[g].x += xv[g].x * wv.x;
            acc[g].y += xv[g].y * wv.y;
            acc[g].z += xv[g].z * wv.z;
            acc[g].w += xv[g].w * wv.w;
        }
#pragma unroll
        for (int g = 0; g < G; ++g) xoff[g] += kstep;
        woff += kstep;
    }

#pragma unroll
    for (int off = 32; off >= 16; off >>= 1) {
#pragma unroll
        for (int g = 0; g < G; ++g) {
            acc[g].x += __shfl_down(acc[g].x, off);
            acc[g].y += __shfl_down(acc[g].y, off);
            acc[g].z += __shfl_down(acc[g].z, off);
            acc[g].w += __shfl_down(acc[g].w, off);
        }
    }

    __shared__ float4 wpart[16][G][16];
    if (lane < 16) {
#pragma unroll
        for (int g = 0; g < G; ++g) wpart[wid][g][lane] = acc[g];
    }
    __syncthreads();

    if (tid < 64) {
        const int g = tid >> 4, c = tid & 15;
        float4 sf = wpart[0][g][c];
#pragma unroll
        for (int ww = 1; ww < 16; ++ww) {
            const float4 o = wpart[ww][g][c];
            sf.x += o.x; sf.y += o.y; sf.z += o.z; sf.w += o.w;
        }
        ws[((size_t)kr * BATCH + b0 + g) * 128 + nc * 16 + c] = sf;
    }
}

__global__ __launch_bounds__(1024)
void k2_finish(const float* __restrict__ v, const float* __restrict__ z,
               const float* __restrict__ z_out, const float* __restrict__ w,
               const float* __restrict__ ws, float* __restrict__ out)
{
    const int nc  = blockIdx.x;
    const int b   = blockIdx.y;
    const int nb  = nc * 64;
    const int tid = threadIdx.x;

    __shared__ float zlds[NN];
    __shared__ float r2[1024];

    if (tid < NN)
        zlds[tid] = BETA * z_out[b * NN + tid] + z[b * NN + tid];
    __syncthreads();

    const int n_loc = tid & 63;
    const int n     = nb + n_loc;
    const int jg    = tid >> 6;
    float d2 = 0.f;
#pragma unroll 4
    for (int j = jg; j < NN - 1; j += 16)
        d2 += zlds[j + (j >= n)] * w[(size_t)(N_IN + j) * NN + n];
    r2[tid] = d2;
    __syncthreads();

    if (tid < 64) {
        float d1 = 0.f;
#pragma unroll
        for (int kr = 0; kr < 4; ++kr)
            d1 += ws[((size_t)kr * BATCH + b) * NN + n];
        float d2s = 0.f;
#pragma unroll
        for (int g = 0; g < 16; ++g) d2s += r2[g * 64 + n_loc];
        const float vv    = v[b * NN + n];
        const float zz    = z[b * NN + n];
        const float v_new = ALPHA * vv + d1 + d2s - V_TH * zz;
        out[b * NN + n]                  = v_new;
        out[BATCH * NN + b * NN + n]     = (v_new - V_TH > 0.f) ? 1.f : 0.f;
        out[2 * BATCH * NN + b * NN + n] = zlds[n];
    }
}

extern "C" void kernel_launch(void* const* d_in, const int* in_sizes, int n_in,
                              void* d_out, int out_size, void* d_ws, size_t ws_size,
                              hipStream_t stream) {
    (void)in_sizes; (void)n_in; (void)out_size;
    const float* x     = (const float*)d_in[0];
    const float* v     = (const float*)d_in[1];
    const float* z     = (const float*)d_in[2];
    const float* z_out = (const float*)d_in[3];
    const float* w     = (const float*)d_in[4];
    float* out = (float*)d_out;
    float* wsf = (float*)d_ws;

    const size_t need32 = (size_t)32 * BATCH * NN * sizeof(float);   // 4 MB
    if (ws_size >= need32) {
        dim3 g1(32, BATCH / G);          // 512 blocks
        k1_stream<<<g1, 1024, 0, stream>>>(x, w, z, z_out, (float4*)wsf);
        k3_epi<<<BATCH * NN / 128, 128, 0, stream>>>(v, z, z_out, wsf, out);
    } else {
        dim3 g1(8, BATCH / G, 4);        // R10 fallback
        k1_fallback<<<g1, 1024, 0, stream>>>(x, w, (float4*)wsf);
        dim3 g2(8, BATCH);
        k2_finish<<<g2, 1024, 0, stream>>>(v, z, z_out, w, wsf, out);
    }
}